// Round 5
// baseline (451.617 us; speedup 1.0000x reference)
//
#include <hip/hip_runtime.h>
#include <hip/hip_bf16.h>

// MultiHeadAttention fused pipeline, MI355X gfx950.
// B=8, S=1024 (N=1023 + 1 global), HID=512, H=8, D=64.
// Stages: qkv_proj (merged, 768 blocks) -> qh/kh [B][H][S][D], vhT [B][H][D][S];
//         attn_fused -> ctx bf16 [B][S][512]; gemm_proj<2> -> f32 out.
// No-max softmax: scores bounded, exp2 with log2e folded into Q scale and bias table.
// R4: t-SPLIT attention — 1024-thread blocks, 16 waves = 8 heads x 2 t-halves
//     (512 t each). Doubles TLP to 4 waves/SIMD (latency-bound kernel).
//     Partials combine additively (no max tracking): upper waves hand off
//     bf16 partial ctx + f32 partial lsum through the dead pbuf LDS region.
//     pbuf shrunk to bf16 [32][34] (b16 writes, dword pair reads, conflict-free).
//     V single-buffered (VGPR <= 128 to keep 4 waves/SIMD).

typedef __attribute__((ext_vector_type(8)))  __bf16 bf16x8;
typedef __attribute__((ext_vector_type(16))) float  f32x16;

__device__ inline f32x16 zero16(){
  f32x16 z;
  #pragma unroll
  for (int i=0;i<16;i++) z[i] = 0.0f;
  return z;
}

__device__ inline unsigned short f2bf(float x){           // RNE f32->bf16
  unsigned u = __float_as_uint(x);
  u += 0x7fffu + ((u>>16)&1u);
  return (unsigned short)(u>>16);
}
__device__ inline unsigned f2bf_pair(float a, float b){   // pack 2 bf16 into dword
  unsigned ua = __float_as_uint(a); ua += 0x7fffu + ((ua>>16)&1u);
  unsigned ub = __float_as_uint(b); ub += 0x7fffu + ((ub>>16)&1u);
  return (ua>>16) | (ub & 0xffff0000u);
}
__device__ inline float bf2f(unsigned short u){
  return __uint_as_float(((unsigned)u)<<16);
}

__device__ inline void bar_lgkm(){   // LDS-visibility barrier WITHOUT vmcnt drain
  asm volatile("s_waitcnt lgkmcnt(0)" ::: "memory");
  __builtin_amdgcn_s_barrier();
}

// ---------------------------------------------------------------------------
// Merged Q/K/V projection. 768 blocks (256 each), 256 threads, 128x128 tile.
// sel=0: qh = (q Wq^T + bq)*scaleq   [B][H][S][D]
// sel=1: kh = (k Wk^T + bk)          [B][H][S][D]
// sel=2: vhT = (v Wv^T + bv)^T       [B][H][D][S]  (computed as Wv * v^T)
// ---------------------------------------------------------------------------
__global__ __launch_bounds__(256)
void qkv_proj(const float* xq, const float* xk, const float* xv,
              const float* Wq, const float* Wk, const float* Wv,
              const float* bq, const float* bk, const float* bv,
              unsigned short* qh, unsigned short* kh, unsigned short* vhT,
              float scaleq)
{
  __shared__ unsigned short lda[128*40];   // 40-pad rows
  __shared__ unsigned short ldb[128*40];
  const int bid = blockIdx.x;
  const int sel = bid >> 8;                // uniform per block
  const int t   = bid & 255;
  const float *RA, *RB, *bias;
  int r0, c0;
  if (sel == 0){ RA = xq; RB = Wq; bias = bq; r0 = (t&63)*128; c0 = (t>>6)*128; }
  else if (sel == 1){ RA = xk; RB = Wk; bias = bk; r0 = (t&63)*128; c0 = (t>>6)*128; }
  else { RA = Wv; RB = xv; bias = bv; r0 = (t&3)*128; c0 = (t>>2)*128; }

  const int tid  = threadIdx.x;
  const int w    = tid>>6, lane = tid&63, lo = lane&31, hi = lane>>5;
  const int wr   = (w>>1)*64, wc = (w&1)*64;
  const int arow = tid>>1, kb = (tid&1)*16;

  f32x16 acc[2][2];
  #pragma unroll
  for (int i=0;i<2;i++)
    #pragma unroll
    for (int j=0;j<2;j++) acc[i][j] = zero16();

  float4 ra[4], rb4[4];
  {
    const float4* p = (const float4*)(RA + (r0+arow)*512 + kb);
    ra[0]=p[0]; ra[1]=p[1]; ra[2]=p[2]; ra[3]=p[3];
    const float4* pq = (const float4*)(RB + (c0+arow)*512 + kb);
    rb4[0]=pq[0]; rb4[1]=pq[1]; rb4[2]=pq[2]; rb4[3]=pq[3];
  }

  for (int ks=0; ks<16; ++ks){
    bar_lgkm();    // prev LDS tiles consumed
    {
      uint4 w0, w1;
      w0.x = f2bf_pair(ra[0].x, ra[0].y); w0.y = f2bf_pair(ra[0].z, ra[0].w);
      w0.z = f2bf_pair(ra[1].x, ra[1].y); w0.w = f2bf_pair(ra[1].z, ra[1].w);
      w1.x = f2bf_pair(ra[2].x, ra[2].y); w1.y = f2bf_pair(ra[2].z, ra[2].w);
      w1.z = f2bf_pair(ra[3].x, ra[3].y); w1.w = f2bf_pair(ra[3].z, ra[3].w);
      uint4* pa = (uint4*)&lda[arow*40 + kb];
      pa[0] = w0; pa[1] = w1;
      uint4 v0, v1;
      v0.x = f2bf_pair(rb4[0].x, rb4[0].y); v0.y = f2bf_pair(rb4[0].z, rb4[0].w);
      v0.z = f2bf_pair(rb4[1].x, rb4[1].y); v0.w = f2bf_pair(rb4[1].z, rb4[1].w);
      v1.x = f2bf_pair(rb4[2].x, rb4[2].y); v1.y = f2bf_pair(rb4[2].z, rb4[2].w);
      v1.z = f2bf_pair(rb4[3].x, rb4[3].y); v1.w = f2bf_pair(rb4[3].z, rb4[3].w);
      uint4* pb = (uint4*)&ldb[arow*40 + kb];
      pb[0] = v0; pb[1] = v1;
    }
    if (ks < 15){
      const int k0 = (ks+1)*32;
      const float4* p = (const float4*)(RA + (r0+arow)*512 + k0 + kb);
      ra[0]=p[0]; ra[1]=p[1]; ra[2]=p[2]; ra[3]=p[3];
      const float4* pq = (const float4*)(RB + (c0+arow)*512 + k0 + kb);
      rb4[0]=pq[0]; rb4[1]=pq[1]; rb4[2]=pq[2]; rb4[3]=pq[3];
    }
    bar_lgkm();    // LDS writes visible; prefetch stays in flight (no vmcnt drain)
    #pragma unroll
    for (int kf=0; kf<2; ++kf){
      bf16x8 af0 = *(const bf16x8*)&lda[(wr+lo)*40    + kf*16 + hi*8];
      bf16x8 af1 = *(const bf16x8*)&lda[(wr+32+lo)*40 + kf*16 + hi*8];
      bf16x8 bg0 = *(const bf16x8*)&ldb[(wc+lo)*40    + kf*16 + hi*8];
      bf16x8 bg1 = *(const bf16x8*)&ldb[(wc+32+lo)*40 + kf*16 + hi*8];
      acc[0][0] = __builtin_amdgcn_mfma_f32_32x32x16_bf16(af0, bg0, acc[0][0], 0,0,0);
      acc[0][1] = __builtin_amdgcn_mfma_f32_32x32x16_bf16(af0, bg1, acc[0][1], 0,0,0);
      acc[1][0] = __builtin_amdgcn_mfma_f32_32x32x16_bf16(af1, bg0, acc[1][0], 0,0,0);
      acc[1][1] = __builtin_amdgcn_mfma_f32_32x32x16_bf16(af1, bg1, acc[1][1], 0,0,0);
    }
  }

  // epilogue; C/D layout: col = lane&31, row = (r&3)+8*(r>>2)+4*(lane>>5)
  #pragma unroll
  for (int mi=0;mi<2;mi++){
    #pragma unroll
    for (int ni=0;ni<2;ni++){
      #pragma unroll
      for (int r=0;r<16;r++){
        const int rl = wr + mi*32 + (r&3) + 8*(r>>2) + 4*hi;
        const int cl = wc + ni*32 + lo;
        const int rg = r0 + rl, cg = c0 + cl;
        float v = acc[mi][ni][r];
        if (sel == 0){
          v = (v + bias[cg]) * scaleq;
          const int bb = rg>>10, s = rg&1023, h = cg>>6, d = cg&63;
          qh[(((bb*8+h)*1024)+s)*64 + d] = f2bf(v);
        } else if (sel == 1){
          v = v + bias[cg];
          const int bb = rg>>10, s = rg&1023, h = cg>>6, d = cg&63;
          kh[(((bb*8+h)*1024)+s)*64 + d] = f2bf(v);
        } else {
          v = v + bias[rg];
          const int h = rg>>6, d = rg&63, bb = cg>>10, s = cg&1023;
          vhT[(((bb*8+h)*64)+d)*1024 + s] = f2bf(v);
        }
      }
    }
  }
}

// ---------------------------------------------------------------------------
// Out projection: out[8192][512] = ctx(bf16) Wo^T + bo, f32 out.
// ---------------------------------------------------------------------------
template<int MODE>
__global__ __launch_bounds__(256)
void gemm_proj(const void* RA_, const float* RB, const float* bias,
               void* OUT, float outscale)
{
  __shared__ unsigned short lda[128*40];
  __shared__ unsigned short ldb[128*40];
  const int tid  = threadIdx.x;
  const int r0   = blockIdx.x*128, c0 = blockIdx.y*128;
  const int w    = tid>>6, lane = tid&63, lo = lane&31, hi = lane>>5;
  const int wr   = (w>>1)*64, wc = (w&1)*64;
  const int arow = tid>>1, kb = (tid&1)*16;

  f32x16 acc[2][2];
  #pragma unroll
  for (int i=0;i<2;i++)
    #pragma unroll
    for (int j=0;j<2;j++) acc[i][j] = zero16();

  float4 rb4[4];
  uint4  ra16[2];

  {
    const uint4* p = (const uint4*)((const unsigned short*)RA_ + (r0+arow)*512 + kb);
    ra16[0]=p[0]; ra16[1]=p[1];
    const float4* pq = (const float4*)(RB + (c0+arow)*512 + kb);
    rb4[0]=pq[0]; rb4[1]=pq[1]; rb4[2]=pq[2]; rb4[3]=pq[3];
  }

  for (int ks=0; ks<16; ++ks){
    bar_lgkm();
    {
      uint4* pa = (uint4*)&lda[arow*40 + kb];
      pa[0] = ra16[0]; pa[1] = ra16[1];
      uint4 v0, v1;
      v0.x = f2bf_pair(rb4[0].x, rb4[0].y); v0.y = f2bf_pair(rb4[0].z, rb4[0].w);
      v0.z = f2bf_pair(rb4[1].x, rb4[1].y); v0.w = f2bf_pair(rb4[1].z, rb4[1].w);
      v1.x = f2bf_pair(rb4[2].x, rb4[2].y); v1.y = f2bf_pair(rb4[2].z, rb4[2].w);
      v1.z = f2bf_pair(rb4[3].x, rb4[3].y); v1.w = f2bf_pair(rb4[3].z, rb4[3].w);
      uint4* pb = (uint4*)&ldb[arow*40 + kb];
      pb[0] = v0; pb[1] = v1;
    }
    if (ks < 15){
      const int k0 = (ks+1)*32;
      const uint4* p = (const uint4*)((const unsigned short*)RA_ + (r0+arow)*512 + k0 + kb);
      ra16[0]=p[0]; ra16[1]=p[1];
      const float4* pq = (const float4*)(RB + (c0+arow)*512 + k0 + kb);
      rb4[0]=pq[0]; rb4[1]=pq[1]; rb4[2]=pq[2]; rb4[3]=pq[3];
    }
    bar_lgkm();
    #pragma unroll
    for (int kf=0; kf<2; ++kf){
      bf16x8 af0 = *(const bf16x8*)&lda[(wr+lo)*40    + kf*16 + hi*8];
      bf16x8 af1 = *(const bf16x8*)&lda[(wr+32+lo)*40 + kf*16 + hi*8];
      bf16x8 bg0 = *(const bf16x8*)&ldb[(wc+lo)*40    + kf*16 + hi*8];
      bf16x8 bg1 = *(const bf16x8*)&ldb[(wc+32+lo)*40 + kf*16 + hi*8];
      acc[0][0] = __builtin_amdgcn_mfma_f32_32x32x16_bf16(af0, bg0, acc[0][0], 0,0,0);
      acc[0][1] = __builtin_amdgcn_mfma_f32_32x32x16_bf16(af0, bg1, acc[0][1], 0,0,0);
      acc[1][0] = __builtin_amdgcn_mfma_f32_32x32x16_bf16(af1, bg0, acc[1][0], 0,0,0);
      acc[1][1] = __builtin_amdgcn_mfma_f32_32x32x16_bf16(af1, bg1, acc[1][1], 0,0,0);
    }
  }

  #pragma unroll
  for (int mi=0;mi<2;mi++){
    #pragma unroll
    for (int ni=0;ni<2;ni++){
      #pragma unroll
      for (int r=0;r<16;r++){
        const int rl = wr + mi*32 + (r&3) + 8*(r>>2) + 4*hi;
        const int cl = wc + ni*32 + lo;
        const int rg = r0 + rl, cg = c0 + cl;
        ((float*)OUT)[rg*512 + cg] = acc[mi][ni][r] + bias[cg];
      }
    }
  }
}

// ---------------------------------------------------------------------------
// Fused attention, t-split. 1024 threads = 16 waves = 8 heads x 2 t-halves.
// Main loop barrier-free (per-wave ab/K prefetch, V single-buffered, per-wave
// bf16 pbuf). Combine: split-1 waves hand off bf16 partial ctx + f32 partial
// lsum through the pbuf LDS region (2 barriers), split-0 normalizes + stores.
// ---------------------------------------------------------------------------
__global__ __launch_bounds__(1024, 4)
void attn_fused(const unsigned short* qh, const unsigned short* kh,
                const unsigned short* vhT, const int* ab,
                const float* bias_table, const float* vbias,
                unsigned short* ctx)
{
  __shared__ float tbl[8*260];              // per-head: [0..254]=table*log2e, 255=-inf, 256=vbias*log2e
  __shared__ unsigned short shp[16*32*34];  // per-wave bf16 pbuf [32][34]; reused as combine region

  const int tid = threadIdx.x;
  const int b   = blockIdx.y;
  const int s0  = blockIdx.x*32;

  for (int i = tid; i < 8*257; i += 1024){
    const int h = i/257, idx = i - h*257;
    float v;
    if (idx < 255)       v = bias_table[idx*8 + h];
    else if (idx == 255) v = -1.0e30f;      // ab==255 -> -inf mask
    else                 v = vbias[h];      // global row/col
    tbl[h*260 + idx] = v * 1.4426950408889634f;
  }
  __syncthreads();   // tbl ready

  const int w = tid>>6, lane = tid&63, lo = lane&31, hi = lane>>5;
  const int h = w & 7, split = w >> 3;
  const int tstart = split*512;
  const unsigned short* qbase = qh  + (size_t)(b*8+h)*1024*64;
  const unsigned short* kbase = kh  + (size_t)(b*8+h)*1024*64;
  const unsigned short* vbase = vhT + (size_t)(b*8+h)*64*1024;
  unsigned short* pb = shp + w*(32*34);
  const unsigned*  pw = (const unsigned*)pb;

  // Q fragments (A operand, rows = s0+lo, k=d), held across the whole t loop
  bf16x8 qf[4];
  #pragma unroll
  for (int kf=0; kf<4; ++kf)
    qf[kf] = *(const bf16x8*)&qbase[(s0+lo)*64 + kf*16 + hi*8];

  f32x16 accv[2]; accv[0] = zero16(); accv[1] = zero16();
  float lsum[16];
  #pragma unroll
  for (int r=0;r<16;r++) lsum[r] = 0.0f;

  // ---- prefetch tile 0: ab indices (coalesced, lane=t), K ----
  int av[16], nav[16];
  #pragma unroll
  for (int r=0;r<16;r++){
    const int qr = s0 + 4*hi + (r&3) + 8*(r>>2);
    const int tc = tstart + lo;
    av[r] = (qr < 1023 && tc < 1023) ? ab[(size_t)(b*1023 + qr)*1023 + tc] : 256;
  }
  bf16x8 kc[4], kn[4];
  #pragma unroll
  for (int i=0;i<4;i++) kc[i] = *(const bf16x8*)&kbase[(tstart+lo)*64 + i*16 + hi*8];

  for (int tt=0; tt<512; tt+=32){
    const int tg = tstart + tt;
    const int tn = tstart + ((tt+32)&511);   // wrapped K prefetch target (last iter unused)

    // scores tile [32q x 32t] = Q * K^T (K prefetched last iter)
    f32x16 sc = zero16();
    sc = __builtin_amdgcn_mfma_f32_32x32x16_bf16(qf[0], kc[0], sc, 0,0,0);
    sc = __builtin_amdgcn_mfma_f32_32x32x16_bf16(qf[1], kc[1], sc, 0,0,0);
    sc = __builtin_amdgcn_mfma_f32_32x32x16_bf16(qf[2], kc[2], sc, 0,0,0);
    sc = __builtin_amdgcn_mfma_f32_32x32x16_bf16(qf[3], kc[3], sc, 0,0,0);
    // issue next K loads + current V loads (covered by exp/transpose section)
    #pragma unroll
    for (int i=0;i<4;i++) kn[i] = *(const bf16x8*)&kbase[(tn+lo)*64 + i*16 + hi*8];
    bf16x8 vf[4];
    #pragma unroll
    for (int dc=0;dc<2;dc++)
      #pragma unroll
      for (int j=0;j<2;j++)
        vf[dc*2+j] = *(const bf16x8*)&vbase[(dc*32+lo)*1024 + tg + j*16 + hi*8];

    // bias lookup (idx in registers) + exp2; truncate p to bf16 consistently
    #pragma unroll
    for (int r=0;r<16;r++){
      const int rq  = (r&3) + 8*(r>>2) + 4*hi;   // q row of this acc reg
      const float bv = tbl[h*260 + av[r]];
      float p = __builtin_amdgcn_exp2f(sc[r] + bv);
      p = __uint_as_float(__float_as_uint(p) & 0xffff0000u);
      lsum[r] += p;
      pb[rq*34 + lo] = (unsigned short)(__float_as_uint(p)>>16);  // bf16 P
    }
    // issue next ab-index loads (guarded; last iter -> sentinel, unused)
    {
      const int tt2 = tt + 32;
      #pragma unroll
      for (int r=0;r<16;r++){
        const int qr = s0 + 4*hi + (r&3) + 8*(r>>2);
        const int tc = tstart + tt2 + lo;
        nav[r] = (tt2 < 512 && qr < 1023 && tc < 1023)
                 ? ab[(size_t)(b*1023 + qr)*1023 + tc] : 256;
      }
    }
    asm volatile("s_waitcnt lgkmcnt(0)" ::: "memory");  // P bounce RAW within wave

    // read P as A fragments: dword at [lo][c] = packed bf16 pair (t=c, t=c+1)
    unsigned pf2[2][4];
    #pragma unroll
    for (int kf=0; kf<2; ++kf){
      #pragma unroll
      for (int pr=0; pr<4; ++pr)
        pf2[kf][pr] = pw[lo*17 + kf*8 + hi*4 + pr];
    }

    // PV: ctx[32q x 64d] += P * V
    #pragma unroll
    for (int dc=0; dc<2; ++dc){
      #pragma unroll
      for (int kf=0; kf<2; ++kf){
        union { unsigned u[4]; bf16x8 v; } pc;
        pc.u[0]=pf2[kf][0]; pc.u[1]=pf2[kf][1]; pc.u[2]=pf2[kf][2]; pc.u[3]=pf2[kf][3];
        accv[dc] = __builtin_amdgcn_mfma_f32_32x32x16_bf16(pc.v, vf[dc*2+kf], accv[dc], 0,0,0);
      }
    }
    // rotate prefetch buffers
    #pragma unroll
    for (int r=0;r<16;r++) av[r] = nav[r];
    #pragma unroll
    for (int i=0;i<4;i++) kc[i] = kn[i];
  }

  // row sums: reduce over the 32 lanes (t-cols) sharing each row
  #pragma unroll
  for (int r=0;r<16;r++){
    #pragma unroll
    for (int m=1;m<32;m<<=1) lsum[r] += __shfl_xor(lsum[r], m, 64);
  }

  // ---- combine the two t-halves through LDS (pbuf region is dead now) ----
  __syncthreads();                               // all pbuf traffic done
  unsigned short* cp  = shp + h*2112;            // [32][64] bf16 partial ctx
  float*          lsp = (float*)(cp + 2048);     // [32] f32 partial lsum
  if (split == 1){
    #pragma unroll
    for (int dc=0; dc<2; ++dc)
      #pragma unroll
      for (int r=0;r<16;r++){
        const int rq = (r&3) + 8*(r>>2) + 4*hi;
        cp[rq*64 + dc*32 + lo] = f2bf(accv[dc][r]);
      }
    if (lo == 0){
      #pragma unroll
      for (int r=0;r<16;r++){
        const int rq = (r&3) + 8*(r>>2) + 4*hi;
        lsp[rq] = lsum[r];
      }
    }
  }
  __syncthreads();
  if (split == 0){
    #pragma unroll
    for (int r=0;r<16;r++){
      const int rq = (r&3) + 8*(r>>2) + 4*hi;
      const float rn = 1.0f / (lsum[r] + lsp[rq]);
      #pragma unroll
      for (int dc=0; dc<2; ++dc){
        const float v = (accv[dc][r] + bf2f(cp[rq*64 + dc*32 + lo])) * rn;
        ctx[((size_t)b*1024 + s0 + rq)*512 + h*64 + dc*32 + lo] = f2bf(v);
      }
    }
  }
}

extern "C" void kernel_launch(void* const* d_in, const int* in_sizes, int n_in,
                              void* d_out, int out_size, void* d_ws, size_t ws_size,
                              hipStream_t stream)
{
  const float* q    = (const float*)d_in[0];
  const float* k    = (const float*)d_in[1];
  const float* v    = (const float*)d_in[2];
  const int*   ab   = (const int*)  d_in[3];
  const float* Wq   = (const float*)d_in[4];
  const float* bq   = (const float*)d_in[5];
  const float* Wk   = (const float*)d_in[6];
  const float* bk   = (const float*)d_in[7];
  const float* Wv   = (const float*)d_in[8];
  const float* bv   = (const float*)d_in[9];
  const float* Wo   = (const float*)d_in[10];
  const float* bo   = (const float*)d_in[11];
  const float* btab = (const float*)d_in[12];
  const float* vbia = (const float*)d_in[13];

  char* ws = (char*)d_ws;
  unsigned short* qh  = (unsigned short*)(ws);
  unsigned short* kh  = (unsigned short*)(ws + ((size_t)8<<20));
  unsigned short* vhT = (unsigned short*)(ws + ((size_t)16<<20));
  unsigned short* ctx = (unsigned short*)(ws + ((size_t)24<<20));

  const float SCALE_Q = 0.125f * 1.4426950408889634f;  // D^-0.5 * log2(e)

  qkv_proj<<<768, 256, 0, stream>>>(q, k, v, Wq, Wk, Wv, bq, bk, bv,
                                    qh, kh, vhT, SCALE_Q);
  attn_fused<<<dim3(32,8), 1024, 0, stream>>>(qh, kh, vhT, ab, btab, vbia, ctx);
  gemm_proj<2><<<dim3(64,4), 256, 0, stream>>>(ctx, Wo, bo, d_out, 1.0f);
}

// Round 7
// 200.468 us; speedup vs baseline: 2.2528x; 2.2528x over previous
//
#include <hip/hip_runtime.h>
#include <hip/hip_bf16.h>

// MultiHeadAttention fused pipeline, MI355X gfx950.
// B=8, S=1024 (N=1023 + 1 global), HID=512, H=8, D=64.
// Stages: qkv_proj (merged, 768 blocks) -> qh/kh [B][H][S][D], vhT [B][H][D][S];
//         attn_fused (t-split across blocks) -> partial ctx bf16 x2 + partial lsum;
//         out_proj fuses partial-combine + normalize into its A-staging -> f32 out.
// No-max softmax: scores bounded, exp2 with log2e folded into Q scale and bias table.
// R5: t-split ACROSS BLOCKS (grid 32x16, 512-thr blocks = R1's proven structure,
//     VGPR ~80, no spill). 4096 waves = 16/CU = 50% occupancy (vs 25% cap before).
//     R4 post-mortem: 1024-thr + launch_bounds(1024,4) forced VGPR=64 -> 780 MB
//     scratch spill traffic. Never grow the block when per-thread state ~100 VGPR.
// R6: identical resubmit (R5 bench was lost to an infra failure).

typedef __attribute__((ext_vector_type(8)))  __bf16 bf16x8;
typedef __attribute__((ext_vector_type(16))) float  f32x16;

__device__ inline f32x16 zero16(){
  f32x16 z;
  #pragma unroll
  for (int i=0;i<16;i++) z[i] = 0.0f;
  return z;
}

__device__ inline unsigned short f2bf(float x){           // RNE f32->bf16
  unsigned u = __float_as_uint(x);
  u += 0x7fffu + ((u>>16)&1u);
  return (unsigned short)(u>>16);
}
__device__ inline unsigned f2bf_pair(float a, float b){   // pack 2 bf16 into dword
  unsigned ua = __float_as_uint(a); ua += 0x7fffu + ((ua>>16)&1u);
  unsigned ub = __float_as_uint(b); ub += 0x7fffu + ((ub>>16)&1u);
  return (ua>>16) | (ub & 0xffff0000u);
}
// combine two packed-bf16 dwords: (a+b)*rn per element, repacked bf16
__device__ inline unsigned comb2(unsigned a, unsigned b, float rn){
  const float a0 = __uint_as_float(a<<16), a1 = __uint_as_float(a & 0xffff0000u);
  const float b0 = __uint_as_float(b<<16), b1 = __uint_as_float(b & 0xffff0000u);
  return f2bf_pair((a0+b0)*rn, (a1+b1)*rn);
}

__device__ inline void bar_lgkm(){   // LDS-visibility barrier WITHOUT vmcnt drain
  asm volatile("s_waitcnt lgkmcnt(0)" ::: "memory");
  __builtin_amdgcn_s_barrier();
}

// ---------------------------------------------------------------------------
// Merged Q/K/V projection. 768 blocks (256 each), 256 threads, 128x128 tile.
// sel=0: qh = (q Wq^T + bq)*scaleq   [B][H][S][D]
// sel=1: kh = (k Wk^T + bk)          [B][H][S][D]
// sel=2: vhT = (v Wv^T + bv)^T       [B][H][D][S]  (computed as Wv * v^T)
// ---------------------------------------------------------------------------
__global__ __launch_bounds__(256)
void qkv_proj(const float* xq, const float* xk, const float* xv,
              const float* Wq, const float* Wk, const float* Wv,
              const float* bq, const float* bk, const float* bv,
              unsigned short* qh, unsigned short* kh, unsigned short* vhT,
              float scaleq)
{
  __shared__ unsigned short lda[128*40];   // 40-pad rows
  __shared__ unsigned short ldb[128*40];
  const int bid = blockIdx.x;
  const int sel = bid >> 8;                // uniform per block
  const int t   = bid & 255;
  const float *RA, *RB, *bias;
  int r0, c0;
  if (sel == 0){ RA = xq; RB = Wq; bias = bq; r0 = (t&63)*128; c0 = (t>>6)*128; }
  else if (sel == 1){ RA = xk; RB = Wk; bias = bk; r0 = (t&63)*128; c0 = (t>>6)*128; }
  else { RA = Wv; RB = xv; bias = bv; r0 = (t&3)*128; c0 = (t>>2)*128; }

  const int tid  = threadIdx.x;
  const int w    = tid>>6, lane = tid&63, lo = lane&31, hi = lane>>5;
  const int wr   = (w>>1)*64, wc = (w&1)*64;
  const int arow = tid>>1, kb = (tid&1)*16;

  f32x16 acc[2][2];
  #pragma unroll
  for (int i=0;i<2;i++)
    #pragma unroll
    for (int j=0;j<2;j++) acc[i][j] = zero16();

  float4 ra[4], rb4[4];
  {
    const float4* p = (const float4*)(RA + (r0+arow)*512 + kb);
    ra[0]=p[0]; ra[1]=p[1]; ra[2]=p[2]; ra[3]=p[3];
    const float4* pq = (const float4*)(RB + (c0+arow)*512 + kb);
    rb4[0]=pq[0]; rb4[1]=pq[1]; rb4[2]=pq[2]; rb4[3]=pq[3];
  }

  for (int ks=0; ks<16; ++ks){
    bar_lgkm();    // prev LDS tiles consumed
    {
      uint4 w0, w1;
      w0.x = f2bf_pair(ra[0].x, ra[0].y); w0.y = f2bf_pair(ra[0].z, ra[0].w);
      w0.z = f2bf_pair(ra[1].x, ra[1].y); w0.w = f2bf_pair(ra[1].z, ra[1].w);
      w1.x = f2bf_pair(ra[2].x, ra[2].y); w1.y = f2bf_pair(ra[2].z, ra[2].w);
      w1.z = f2bf_pair(ra[3].x, ra[3].y); w1.w = f2bf_pair(ra[3].z, ra[3].w);
      uint4* pa = (uint4*)&lda[arow*40 + kb];
      pa[0] = w0; pa[1] = w1;
      uint4 v0, v1;
      v0.x = f2bf_pair(rb4[0].x, rb4[0].y); v0.y = f2bf_pair(rb4[0].z, rb4[0].w);
      v0.z = f2bf_pair(rb4[1].x, rb4[1].y); v0.w = f2bf_pair(rb4[1].z, rb4[1].w);
      v1.x = f2bf_pair(rb4[2].x, rb4[2].y); v1.y = f2bf_pair(rb4[2].z, rb4[2].w);
      v1.z = f2bf_pair(rb4[3].x, rb4[3].y); v1.w = f2bf_pair(rb4[3].z, rb4[3].w);
      uint4* pb = (uint4*)&ldb[arow*40 + kb];
      pb[0] = v0; pb[1] = v1;
    }
    if (ks < 15){
      const int k0 = (ks+1)*32;
      const float4* p = (const float4*)(RA + (r0+arow)*512 + k0 + kb);
      ra[0]=p[0]; ra[1]=p[1]; ra[2]=p[2]; ra[3]=p[3];
      const float4* pq = (const float4*)(RB + (c0+arow)*512 + k0 + kb);
      rb4[0]=pq[0]; rb4[1]=pq[1]; rb4[2]=pq[2]; rb4[3]=pq[3];
    }
    bar_lgkm();    // LDS writes visible; prefetch stays in flight (no vmcnt drain)
    #pragma unroll
    for (int kf=0; kf<2; ++kf){
      bf16x8 af0 = *(const bf16x8*)&lda[(wr+lo)*40    + kf*16 + hi*8];
      bf16x8 af1 = *(const bf16x8*)&lda[(wr+32+lo)*40 + kf*16 + hi*8];
      bf16x8 bg0 = *(const bf16x8*)&ldb[(wc+lo)*40    + kf*16 + hi*8];
      bf16x8 bg1 = *(const bf16x8*)&ldb[(wc+32+lo)*40 + kf*16 + hi*8];
      acc[0][0] = __builtin_amdgcn_mfma_f32_32x32x16_bf16(af0, bg0, acc[0][0], 0,0,0);
      acc[0][1] = __builtin_amdgcn_mfma_f32_32x32x16_bf16(af0, bg1, acc[0][1], 0,0,0);
      acc[1][0] = __builtin_amdgcn_mfma_f32_32x32x16_bf16(af1, bg0, acc[1][0], 0,0,0);
      acc[1][1] = __builtin_amdgcn_mfma_f32_32x32x16_bf16(af1, bg1, acc[1][1], 0,0,0);
    }
  }

  // epilogue; C/D layout: col = lane&31, row = (r&3)+8*(r>>2)+4*(lane>>5)
  #pragma unroll
  for (int mi=0;mi<2;mi++){
    #pragma unroll
    for (int ni=0;ni<2;ni++){
      #pragma unroll
      for (int r=0;r<16;r++){
        const int rl = wr + mi*32 + (r&3) + 8*(r>>2) + 4*hi;
        const int cl = wc + ni*32 + lo;
        const int rg = r0 + rl, cg = c0 + cl;
        float v = acc[mi][ni][r];
        if (sel == 0){
          v = (v + bias[cg]) * scaleq;
          const int bb = rg>>10, s = rg&1023, h = cg>>6, d = cg&63;
          qh[(((bb*8+h)*1024)+s)*64 + d] = f2bf(v);
        } else if (sel == 1){
          v = v + bias[cg];
          const int bb = rg>>10, s = rg&1023, h = cg>>6, d = cg&63;
          kh[(((bb*8+h)*1024)+s)*64 + d] = f2bf(v);
        } else {
          v = v + bias[rg];
          const int h = rg>>6, d = rg&63, bb = cg>>10, s = cg&1023;
          vhT[(((bb*8+h)*64)+d)*1024 + s] = f2bf(v);
        }
      }
    }
  }
}

// ---------------------------------------------------------------------------
// Out projection with fused partial-combine:
//   A[row][k] = (ctx0[row][k] + ctx1[row][k]) / (l0[b,h,s] + l1[b,h,s])
//   out[8192][512] = A Wo^T + bo (f32).
// h = k/64 is constant within each 16-element staging chunk.
// ---------------------------------------------------------------------------
__global__ __launch_bounds__(256)
void out_proj(const unsigned short* ctx0, const unsigned short* ctx1,
              const float* lsump, const float* Wo, const float* bo, float* OUT)
{
  __shared__ unsigned short lda[128*40];
  __shared__ unsigned short ldb[128*40];
  const int tid  = threadIdx.x;
  const int r0   = blockIdx.x*128, c0 = blockIdx.y*128;
  const int w    = tid>>6, lane = tid&63, lo = lane&31, hi = lane>>5;
  const int wr   = (w>>1)*64, wc = (w&1)*64;
  const int arow = tid>>1, kb = (tid&1)*16;
  const int rgs  = r0 + arow, bb = rgs>>10, ss = rgs&1023;
  const float* lb0 = lsump + (size_t)(bb*8)*1024 + ss;        // ts=0, + h*1024
  const float* lb1 = lsump + (size_t)((8+bb)*8)*1024 + ss;    // ts=1

  f32x16 acc[2][2];
  #pragma unroll
  for (int i=0;i<2;i++)
    #pragma unroll
    for (int j=0;j<2;j++) acc[i][j] = zero16();

  uint4 ra0[2], ra1[2];
  float4 rb4[4];
  float l0, l1;

  {
    const uint4* p0 = (const uint4*)(ctx0 + rgs*512 + kb);
    ra0[0]=p0[0]; ra0[1]=p0[1];
    const uint4* p1 = (const uint4*)(ctx1 + rgs*512 + kb);
    ra1[0]=p1[0]; ra1[1]=p1[1];
    const int h = kb>>6;
    l0 = lb0[h*1024]; l1 = lb1[h*1024];
    const float4* pq = (const float4*)(Wo + (c0+arow)*512 + kb);
    rb4[0]=pq[0]; rb4[1]=pq[1]; rb4[2]=pq[2]; rb4[3]=pq[3];
  }

  for (int ks=0; ks<16; ++ks){
    bar_lgkm();
    {
      const float rn = __builtin_amdgcn_rcpf(l0 + l1);
      uint4 w0, w1;
      w0.x = comb2(ra0[0].x, ra1[0].x, rn); w0.y = comb2(ra0[0].y, ra1[0].y, rn);
      w0.z = comb2(ra0[0].z, ra1[0].z, rn); w0.w = comb2(ra0[0].w, ra1[0].w, rn);
      w1.x = comb2(ra0[1].x, ra1[1].x, rn); w1.y = comb2(ra0[1].y, ra1[1].y, rn);
      w1.z = comb2(ra0[1].z, ra1[1].z, rn); w1.w = comb2(ra0[1].w, ra1[1].w, rn);
      uint4* pa = (uint4*)&lda[arow*40 + kb];
      pa[0] = w0; pa[1] = w1;
      uint4 v0, v1;
      v0.x = f2bf_pair(rb4[0].x, rb4[0].y); v0.y = f2bf_pair(rb4[0].z, rb4[0].w);
      v0.z = f2bf_pair(rb4[1].x, rb4[1].y); v0.w = f2bf_pair(rb4[1].z, rb4[1].w);
      v1.x = f2bf_pair(rb4[2].x, rb4[2].y); v1.y = f2bf_pair(rb4[2].z, rb4[2].w);
      v1.z = f2bf_pair(rb4[3].x, rb4[3].y); v1.w = f2bf_pair(rb4[3].z, rb4[3].w);
      uint4* pb = (uint4*)&ldb[arow*40 + kb];
      pb[0] = v0; pb[1] = v1;
    }
    if (ks < 15){
      const int k0 = (ks+1)*32;
      const uint4* p0 = (const uint4*)(ctx0 + rgs*512 + k0 + kb);
      ra0[0]=p0[0]; ra0[1]=p0[1];
      const uint4* p1 = (const uint4*)(ctx1 + rgs*512 + k0 + kb);
      ra1[0]=p1[0]; ra1[1]=p1[1];
      const int h = (k0+kb)>>6;
      l0 = lb0[h*1024]; l1 = lb1[h*1024];
      const float4* pq = (const float4*)(Wo + (c0+arow)*512 + k0 + kb);
      rb4[0]=pq[0]; rb4[1]=pq[1]; rb4[2]=pq[2]; rb4[3]=pq[3];
    }
    bar_lgkm();
    #pragma unroll
    for (int kf=0; kf<2; ++kf){
      bf16x8 af0 = *(const bf16x8*)&lda[(wr+lo)*40    + kf*16 + hi*8];
      bf16x8 af1 = *(const bf16x8*)&lda[(wr+32+lo)*40 + kf*16 + hi*8];
      bf16x8 bg0 = *(const bf16x8*)&ldb[(wc+lo)*40    + kf*16 + hi*8];
      bf16x8 bg1 = *(const bf16x8*)&ldb[(wc+32+lo)*40 + kf*16 + hi*8];
      acc[0][0] = __builtin_amdgcn_mfma_f32_32x32x16_bf16(af0, bg0, acc[0][0], 0,0,0);
      acc[0][1] = __builtin_amdgcn_mfma_f32_32x32x16_bf16(af0, bg1, acc[0][1], 0,0,0);
      acc[1][0] = __builtin_amdgcn_mfma_f32_32x32x16_bf16(af1, bg0, acc[1][0], 0,0,0);
      acc[1][1] = __builtin_amdgcn_mfma_f32_32x32x16_bf16(af1, bg1, acc[1][1], 0,0,0);
    }
  }

  #pragma unroll
  for (int mi=0;mi<2;mi++){
    #pragma unroll
    for (int ni=0;ni<2;ni++){
      #pragma unroll
      for (int r=0;r<16;r++){
        const int rl = wr + mi*32 + (r&3) + 8*(r>>2) + 4*hi;
        const int cl = wc + ni*32 + lo;
        const int rg = r0 + rl, cg = c0 + cl;
        OUT[rg*512 + cg] = acc[mi][ni][r] + bo[cg];
      }
    }
  }
}

// ---------------------------------------------------------------------------
// Fused attention, t-split across blocks. Grid (32 q-tiles, B*2), 512 thr =
// 8 waves = 8 heads; block handles t in [ts*512, ts*512+512). R1 structure:
// abt LDS double-buffer (1 raw barrier/iter), K/V register prefetch.
// Outputs UNNORMALIZED partial ctx (bf16) + partial row-sums (f32).
// ---------------------------------------------------------------------------
__global__ __launch_bounds__(512, 4)
void attn_fused(const unsigned short* qh, const unsigned short* kh,
                const unsigned short* vhT, const int* ab,
                const float* bias_table, const float* vbias,
                unsigned short* ctxp, float* lsump)
{
  __shared__ float tbl[8*260];        // per-head: [0..254]=table*log2e, 255=-inf, 256=vbias*log2e
  __shared__ int   abt[2][32*33];     // bias-index tile, double-buffered, TRANSPOSED [t][q], padded
  __shared__ float pbuf[8][32*33];    // per-wave P bounce, [q][t] f32, padded

  const int tid = threadIdx.x;
  const int b   = blockIdx.y >> 1;
  const int ts  = blockIdx.y & 1;     // t-split half
  const int s0  = blockIdx.x*32;
  const int tb  = ts*512;

  for (int i = tid; i < 8*257; i += 512){
    const int h = i/257, idx = i - h*257;
    float v;
    if (idx < 255)       v = bias_table[idx*8 + h];
    else if (idx == 255) v = -1.0e30f;      // ab==255 -> -inf mask
    else                 v = vbias[h];      // global row/col
    tbl[h*260 + idx] = v * 1.4426950408889634f;
  }

  const int w = tid>>6, lane = tid&63, lo = lane&31, hi = lane>>5;
  const unsigned short* qbase = qh  + (size_t)(b*8+w)*1024*64;
  const unsigned short* kbase = kh  + (size_t)(b*8+w)*1024*64;
  const unsigned short* vbase = vhT + (size_t)(b*8+w)*64*1024;

  // Q fragments (A operand, rows = s0+lo, k=d), held across the whole t loop
  bf16x8 qf[4];
  #pragma unroll
  for (int kf=0; kf<4; ++kf)
    qf[kf] = *(const bf16x8*)&qbase[(s0+lo)*64 + kf*16 + hi*8];

  f32x16 accv[2]; accv[0] = zero16(); accv[1] = zero16();
  float lsum[16];
  #pragma unroll
  for (int r=0;r<16;r++) lsum[r] = 0.0f;

  const int e0   = tid*2;
  const int str  = e0>>5;      // staging q-row
  const int stc  = e0&31;      // staging t-col (even)
  const int srow = s0 + str;
  const size_t abrow = (size_t)(b*1023 + srow)*1023;

  // ---- prefetch tile 0 ----
  int av0 = 256, av1 = 256;
  if (srow < 1023){
    if (tb + stc     < 1023) av0 = ab[abrow + tb + stc];
    if (tb + stc + 1 < 1023) av1 = ab[abrow + tb + stc + 1];
  }
  bf16x8 kc[4], kn[4], vc[4], vn[4];
  #pragma unroll
  for (int i=0;i<4;i++) kc[i] = *(const bf16x8*)&kbase[(tb+lo)*64 + i*16 + hi*8];
  #pragma unroll
  for (int dc=0;dc<2;dc++)
    #pragma unroll
    for (int j=0;j<2;j++)
      vc[dc*2+j] = *(const bf16x8*)&vbase[(dc*32+lo)*1024 + tb + j*16 + hi*8];

  for (int tt=0; tt<512; tt+=32){
    const int cur = (tt>>5)&1;
    const int tn  = tb + ((tt+32)&511);        // wrapped prefetch target (last iter unused)
    // stage abt[cur] from prefetched regs (vmcnt wait happens here, 1 iter of slack)
    abt[cur][(stc  )*33 + str] = av0;
    abt[cur][(stc+1)*33 + str] = av1;
    // issue next ab loads
    int na0 = 256, na1 = 256;
    if (tt < 480 && srow < 1023){
      const int tc = tb + tt + 32 + stc;
      if (tc     < 1023) na0 = ab[abrow + tc];
      if (tc + 1 < 1023) na1 = ab[abrow + tc + 1];
    }

    // scores tile [32q x 32t] = Q * K^T (K prefetched last iter)
    f32x16 sc = zero16();
    sc = __builtin_amdgcn_mfma_f32_32x32x16_bf16(qf[0], kc[0], sc, 0,0,0);
    sc = __builtin_amdgcn_mfma_f32_32x32x16_bf16(qf[1], kc[1], sc, 0,0,0);
    sc = __builtin_amdgcn_mfma_f32_32x32x16_bf16(qf[2], kc[2], sc, 0,0,0);
    sc = __builtin_amdgcn_mfma_f32_32x32x16_bf16(qf[3], kc[3], sc, 0,0,0);
    // issue next K loads (in flight across the barrier)
    #pragma unroll
    for (int i=0;i<4;i++) kn[i] = *(const bf16x8*)&kbase[(tn+lo)*64 + i*16 + hi*8];

    // abt[cur] visible to all waves; vmcnt NOT drained (raw barrier)
    bar_lgkm();

    // bias lookup + exp2; truncate p to bf16 (consistently for lsum and P)
    #pragma unroll
    for (int r=0;r<16;r++){
      const int rq  = (r&3) + 8*(r>>2) + 4*hi;   // q row of this acc reg
      const int idx = abt[cur][lo*33 + rq];      // read transposed: row=t(lo), col=q
      const float bv = tbl[w*260 + idx];
      float p = __builtin_amdgcn_exp2f(sc[r] + bv);
      p = __uint_as_float(__float_as_uint(p) & 0xffff0000u);
      lsum[r] += p;
      pbuf[w][rq*33 + lo] = p;                   // [q][t], conflict-free (33 pad)
    }
    asm volatile("s_waitcnt lgkmcnt(0)" ::: "memory");  // P bounce RAW within wave

    // read P as A fragments (row=lo, k=t consecutive), pack truncated bf16 pairs
    unsigned pf[2][4];
    #pragma unroll
    for (int kf=0; kf<2; ++kf){
      #pragma unroll
      for (int pr=0; pr<4; ++pr){
        const float a = pbuf[w][lo*33 + kf*16 + hi*8 + 2*pr];
        const float c = pbuf[w][lo*33 + kf*16 + hi*8 + 2*pr + 1];
        pf[kf][pr] = (__float_as_uint(a)>>16) | (__float_as_uint(c) & 0xffff0000u);
      }
    }
    // issue next V loads
    #pragma unroll
    for (int dc=0;dc<2;dc++)
      #pragma unroll
      for (int j=0;j<2;j++)
        vn[dc*2+j] = *(const bf16x8*)&vbase[(dc*32+lo)*1024 + tn + j*16 + hi*8];

    // PV: ctx[32q x 64d] += P * V
    #pragma unroll
    for (int dc=0; dc<2; ++dc){
      #pragma unroll
      for (int kf=0; kf<2; ++kf){
        union { unsigned u[4]; bf16x8 v; } pc;
        pc.u[0]=pf[kf][0]; pc.u[1]=pf[kf][1]; pc.u[2]=pf[kf][2]; pc.u[3]=pf[kf][3];
        accv[dc] = __builtin_amdgcn_mfma_f32_32x32x16_bf16(pc.v, vc[dc*2+kf], accv[dc], 0,0,0);
      }
    }
    // rotate prefetch buffers
    av0 = na0; av1 = na1;
    #pragma unroll
    for (int i=0;i<4;i++){ kc[i] = kn[i]; vc[i] = vn[i]; }
  }

  // partial row sums: reduce over the 32 lanes (t-cols) sharing each row
  #pragma unroll
  for (int r=0;r<16;r++){
    #pragma unroll
    for (int m=1;m<32;m<<=1) lsum[r] += __shfl_xor(lsum[r], m, 64);
  }
  // store UNNORMALIZED partial ctx bf16 (this half's slice) + partial lsum
  unsigned short* cbase = ctxp + (size_t)ts*4194304;   // 8*1024*512 elements per half
  #pragma unroll
  for (int dc=0; dc<2; ++dc){
    #pragma unroll
    for (int r=0;r<16;r++){
      const int rq = (r&3) + 8*(r>>2) + 4*hi;
      cbase[((size_t)b*1024 + s0 + rq)*512 + w*64 + dc*32 + lo] = f2bf(accv[dc][r]);
    }
  }
  if (lo == 0){
    #pragma unroll
    for (int r=0;r<16;r++){
      const int rq = (r&3) + 8*(r>>2) + 4*hi;
      lsump[((size_t)(ts*8 + b)*8 + w)*1024 + s0 + rq] = lsum[r];
    }
  }
}

extern "C" void kernel_launch(void* const* d_in, const int* in_sizes, int n_in,
                              void* d_out, int out_size, void* d_ws, size_t ws_size,
                              hipStream_t stream)
{
  const float* q    = (const float*)d_in[0];
  const float* k    = (const float*)d_in[1];
  const float* v    = (const float*)d_in[2];
  const int*   ab   = (const int*)  d_in[3];
  const float* Wq   = (const float*)d_in[4];
  const float* bq   = (const float*)d_in[5];
  const float* Wk   = (const float*)d_in[6];
  const float* bk   = (const float*)d_in[7];
  const float* Wv   = (const float*)d_in[8];
  const float* bv   = (const float*)d_in[9];
  const float* Wo   = (const float*)d_in[10];
  const float* bo   = (const float*)d_in[11];
  const float* btab = (const float*)d_in[12];
  const float* vbia = (const float*)d_in[13];

  char* ws = (char*)d_ws;
  unsigned short* qh   = (unsigned short*)(ws);                    //  8 MB
  unsigned short* kh   = (unsigned short*)(ws + ((size_t) 8<<20)); //  8 MB
  unsigned short* vhT  = (unsigned short*)(ws + ((size_t)16<<20)); //  8 MB
  unsigned short* ctxp = (unsigned short*)(ws + ((size_t)24<<20)); // 16 MB (2 halves)
  float*          lsmp = (float*)         (ws + ((size_t)40<<20)); // 512 KB

  const float SCALE_Q = 0.125f * 1.4426950408889634f;  // D^-0.5 * log2(e)

  qkv_proj<<<768, 256, 0, stream>>>(q, k, v, Wq, Wk, Wv, bq, bk, bv,
                                    qh, kh, vhT, SCALE_Q);
  attn_fused<<<dim3(32,16), 512, 0, stream>>>(qh, kh, vhT, ab, btab, vbia,
                                              ctxp, lsmp);
  out_proj<<<dim3(64,4), 256, 0, stream>>>(ctxp, ctxp + (size_t)4194304,
                                           lsmp, Wo, bo, (float*)d_out);
}

// Round 9
// 148.089 us; speedup vs baseline: 3.0496x; 1.3537x over previous
//
#include <hip/hip_runtime.h>
#include <hip/hip_bf16.h>

// MultiHeadAttention fused pipeline, MI355X gfx950.
// B=8, S=1024 (N=1023 + 1 global), HID=512, H=8, D=64.
// Stages: qkv_proj (merged, 768 blocks) -> qh/kh [B][H][S][D], vhT [B][H][D][S];
//         attn_fused (t-split across blocks) -> partial ctx bf16 x2 + partial lsum;
//         out_proj fuses partial-combine + normalize into its A-staging -> f32 out.
// No-max softmax: scores bounded, exp2 with log2e folded into Q scale and bias table.
// R5: t-split ACROSS BLOCKS (grid 32x16, 512-thr blocks, R1 loop structure).
// R7: drop the __launch_bounds__ min-waves hint. R5's (512,4) forced VGPR=64
//     (state needs ~90) -> 260 MB spill traffic (FETCH 307 MB, WRITE 44.5 MB).
//     Lesson (R4+R5): occupancy hints clamp the allocator below need and spill;
//     size the grid for occupancy, let VGPR float (~90 -> 4 waves/SIMD anyway).
// R8: identical resubmit (R7 bench was lost to an infra failure).

typedef __attribute__((ext_vector_type(8)))  __bf16 bf16x8;
typedef __attribute__((ext_vector_type(16))) float  f32x16;

__device__ inline f32x16 zero16(){
  f32x16 z;
  #pragma unroll
  for (int i=0;i<16;i++) z[i] = 0.0f;
  return z;
}

__device__ inline unsigned short f2bf(float x){           // RNE f32->bf16
  unsigned u = __float_as_uint(x);
  u += 0x7fffu + ((u>>16)&1u);
  return (unsigned short)(u>>16);
}
__device__ inline unsigned f2bf_pair(float a, float b){   // pack 2 bf16 into dword
  unsigned ua = __float_as_uint(a); ua += 0x7fffu + ((ua>>16)&1u);
  unsigned ub = __float_as_uint(b); ub += 0x7fffu + ((ub>>16)&1u);
  return (ua>>16) | (ub & 0xffff0000u);
}
// combine two packed-bf16 dwords: (a+b)*rn per element, repacked bf16
__device__ inline unsigned comb2(unsigned a, unsigned b, float rn){
  const float a0 = __uint_as_float(a<<16), a1 = __uint_as_float(a & 0xffff0000u);
  const float b0 = __uint_as_float(b<<16), b1 = __uint_as_float(b & 0xffff0000u);
  return f2bf_pair((a0+b0)*rn, (a1+b1)*rn);
}

__device__ inline void bar_lgkm(){   // LDS-visibility barrier WITHOUT vmcnt drain
  asm volatile("s_waitcnt lgkmcnt(0)" ::: "memory");
  __builtin_amdgcn_s_barrier();
}

// ---------------------------------------------------------------------------
// Merged Q/K/V projection. 768 blocks (256 each), 256 threads, 128x128 tile.
// sel=0: qh = (q Wq^T + bq)*scaleq   [B][H][S][D]
// sel=1: kh = (k Wk^T + bk)          [B][H][S][D]
// sel=2: vhT = (v Wv^T + bv)^T       [B][H][D][S]  (computed as Wv * v^T)
// ---------------------------------------------------------------------------
__global__ __launch_bounds__(256)
void qkv_proj(const float* xq, const float* xk, const float* xv,
              const float* Wq, const float* Wk, const float* Wv,
              const float* bq, const float* bk, const float* bv,
              unsigned short* qh, unsigned short* kh, unsigned short* vhT,
              float scaleq)
{
  __shared__ unsigned short lda[128*40];   // 40-pad rows
  __shared__ unsigned short ldb[128*40];
  const int bid = blockIdx.x;
  const int sel = bid >> 8;                // uniform per block
  const int t   = bid & 255;
  const float *RA, *RB, *bias;
  int r0, c0;
  if (sel == 0){ RA = xq; RB = Wq; bias = bq; r0 = (t&63)*128; c0 = (t>>6)*128; }
  else if (sel == 1){ RA = xk; RB = Wk; bias = bk; r0 = (t&63)*128; c0 = (t>>6)*128; }
  else { RA = Wv; RB = xv; bias = bv; r0 = (t&3)*128; c0 = (t>>2)*128; }

  const int tid  = threadIdx.x;
  const int w    = tid>>6, lane = tid&63, lo = lane&31, hi = lane>>5;
  const int wr   = (w>>1)*64, wc = (w&1)*64;
  const int arow = tid>>1, kb = (tid&1)*16;

  f32x16 acc[2][2];
  #pragma unroll
  for (int i=0;i<2;i++)
    #pragma unroll
    for (int j=0;j<2;j++) acc[i][j] = zero16();

  float4 ra[4], rb4[4];
  {
    const float4* p = (const float4*)(RA + (r0+arow)*512 + kb);
    ra[0]=p[0]; ra[1]=p[1]; ra[2]=p[2]; ra[3]=p[3];
    const float4* pq = (const float4*)(RB + (c0+arow)*512 + kb);
    rb4[0]=pq[0]; rb4[1]=pq[1]; rb4[2]=pq[2]; rb4[3]=pq[3];
  }

  for (int ks=0; ks<16; ++ks){
    bar_lgkm();    // prev LDS tiles consumed
    {
      uint4 w0, w1;
      w0.x = f2bf_pair(ra[0].x, ra[0].y); w0.y = f2bf_pair(ra[0].z, ra[0].w);
      w0.z = f2bf_pair(ra[1].x, ra[1].y); w0.w = f2bf_pair(ra[1].z, ra[1].w);
      w1.x = f2bf_pair(ra[2].x, ra[2].y); w1.y = f2bf_pair(ra[2].z, ra[2].w);
      w1.z = f2bf_pair(ra[3].x, ra[3].y); w1.w = f2bf_pair(ra[3].z, ra[3].w);
      uint4* pa = (uint4*)&lda[arow*40 + kb];
      pa[0] = w0; pa[1] = w1;
      uint4 v0, v1;
      v0.x = f2bf_pair(rb4[0].x, rb4[0].y); v0.y = f2bf_pair(rb4[0].z, rb4[0].w);
      v0.z = f2bf_pair(rb4[1].x, rb4[1].y); v0.w = f2bf_pair(rb4[1].z, rb4[1].w);
      v1.x = f2bf_pair(rb4[2].x, rb4[2].y); v1.y = f2bf_pair(rb4[2].z, rb4[2].w);
      v1.z = f2bf_pair(rb4[3].x, rb4[3].y); v1.w = f2bf_pair(rb4[3].z, rb4[3].w);
      uint4* pb = (uint4*)&ldb[arow*40 + kb];
      pb[0] = v0; pb[1] = v1;
    }
    if (ks < 15){
      const int k0 = (ks+1)*32;
      const float4* p = (const float4*)(RA + (r0+arow)*512 + k0 + kb);
      ra[0]=p[0]; ra[1]=p[1]; ra[2]=p[2]; ra[3]=p[3];
      const float4* pq = (const float4*)(RB + (c0+arow)*512 + k0 + kb);
      rb4[0]=pq[0]; rb4[1]=pq[1]; rb4[2]=pq[2]; rb4[3]=pq[3];
    }
    bar_lgkm();    // LDS writes visible; prefetch stays in flight (no vmcnt drain)
    #pragma unroll
    for (int kf=0; kf<2; ++kf){
      bf16x8 af0 = *(const bf16x8*)&lda[(wr+lo)*40    + kf*16 + hi*8];
      bf16x8 af1 = *(const bf16x8*)&lda[(wr+32+lo)*40 + kf*16 + hi*8];
      bf16x8 bg0 = *(const bf16x8*)&ldb[(wc+lo)*40    + kf*16 + hi*8];
      bf16x8 bg1 = *(const bf16x8*)&ldb[(wc+32+lo)*40 + kf*16 + hi*8];
      acc[0][0] = __builtin_amdgcn_mfma_f32_32x32x16_bf16(af0, bg0, acc[0][0], 0,0,0);
      acc[0][1] = __builtin_amdgcn_mfma_f32_32x32x16_bf16(af0, bg1, acc[0][1], 0,0,0);
      acc[1][0] = __builtin_amdgcn_mfma_f32_32x32x16_bf16(af1, bg0, acc[1][0], 0,0,0);
      acc[1][1] = __builtin_amdgcn_mfma_f32_32x32x16_bf16(af1, bg1, acc[1][1], 0,0,0);
    }
  }

  // epilogue; C/D layout: col = lane&31, row = (r&3)+8*(r>>2)+4*(lane>>5)
  #pragma unroll
  for (int mi=0;mi<2;mi++){
    #pragma unroll
    for (int ni=0;ni<2;ni++){
      #pragma unroll
      for (int r=0;r<16;r++){
        const int rl = wr + mi*32 + (r&3) + 8*(r>>2) + 4*hi;
        const int cl = wc + ni*32 + lo;
        const int rg = r0 + rl, cg = c0 + cl;
        float v = acc[mi][ni][r];
        if (sel == 0){
          v = (v + bias[cg]) * scaleq;
          const int bb = rg>>10, s = rg&1023, h = cg>>6, d = cg&63;
          qh[(((bb*8+h)*1024)+s)*64 + d] = f2bf(v);
        } else if (sel == 1){
          v = v + bias[cg];
          const int bb = rg>>10, s = rg&1023, h = cg>>6, d = cg&63;
          kh[(((bb*8+h)*1024)+s)*64 + d] = f2bf(v);
        } else {
          v = v + bias[rg];
          const int h = rg>>6, d = rg&63, bb = cg>>10, s = cg&1023;
          vhT[(((bb*8+h)*64)+d)*1024 + s] = f2bf(v);
        }
      }
    }
  }
}

// ---------------------------------------------------------------------------
// Out projection with fused partial-combine:
//   A[row][k] = (ctx0[row][k] + ctx1[row][k]) / (l0[b,h,s] + l1[b,h,s])
//   out[8192][512] = A Wo^T + bo (f32).
// h = k/64 is constant within each 16-element staging chunk.
// ---------------------------------------------------------------------------
__global__ __launch_bounds__(256)
void out_proj(const unsigned short* ctx0, const unsigned short* ctx1,
              const float* lsump, const float* Wo, const float* bo, float* OUT)
{
  __shared__ unsigned short lda[128*40];
  __shared__ unsigned short ldb[128*40];
  const int tid  = threadIdx.x;
  const int r0   = blockIdx.x*128, c0 = blockIdx.y*128;
  const int w    = tid>>6, lane = tid&63, lo = lane&31, hi = lane>>5;
  const int wr   = (w>>1)*64, wc = (w&1)*64;
  const int arow = tid>>1, kb = (tid&1)*16;
  const int rgs  = r0 + arow, bb = rgs>>10, ss = rgs&1023;
  const float* lb0 = lsump + (size_t)(bb*8)*1024 + ss;        // ts=0, + h*1024
  const float* lb1 = lsump + (size_t)((8+bb)*8)*1024 + ss;    // ts=1

  f32x16 acc[2][2];
  #pragma unroll
  for (int i=0;i<2;i++)
    #pragma unroll
    for (int j=0;j<2;j++) acc[i][j] = zero16();

  uint4 ra0[2], ra1[2];
  float4 rb4[4];
  float l0, l1;

  {
    const uint4* p0 = (const uint4*)(ctx0 + rgs*512 + kb);
    ra0[0]=p0[0]; ra0[1]=p0[1];
    const uint4* p1 = (const uint4*)(ctx1 + rgs*512 + kb);
    ra1[0]=p1[0]; ra1[1]=p1[1];
    const int h = kb>>6;
    l0 = lb0[h*1024]; l1 = lb1[h*1024];
    const float4* pq = (const float4*)(Wo + (c0+arow)*512 + kb);
    rb4[0]=pq[0]; rb4[1]=pq[1]; rb4[2]=pq[2]; rb4[3]=pq[3];
  }

  for (int ks=0; ks<16; ++ks){
    bar_lgkm();
    {
      const float rn = __builtin_amdgcn_rcpf(l0 + l1);
      uint4 w0, w1;
      w0.x = comb2(ra0[0].x, ra1[0].x, rn); w0.y = comb2(ra0[0].y, ra1[0].y, rn);
      w0.z = comb2(ra0[0].z, ra1[0].z, rn); w0.w = comb2(ra0[0].w, ra1[0].w, rn);
      w1.x = comb2(ra0[1].x, ra1[1].x, rn); w1.y = comb2(ra0[1].y, ra1[1].y, rn);
      w1.z = comb2(ra0[1].z, ra1[1].z, rn); w1.w = comb2(ra0[1].w, ra1[1].w, rn);
      uint4* pa = (uint4*)&lda[arow*40 + kb];
      pa[0] = w0; pa[1] = w1;
      uint4 v0, v1;
      v0.x = f2bf_pair(rb4[0].x, rb4[0].y); v0.y = f2bf_pair(rb4[0].z, rb4[0].w);
      v0.z = f2bf_pair(rb4[1].x, rb4[1].y); v0.w = f2bf_pair(rb4[1].z, rb4[1].w);
      v1.x = f2bf_pair(rb4[2].x, rb4[2].y); v1.y = f2bf_pair(rb4[2].z, rb4[2].w);
      v1.z = f2bf_pair(rb4[3].x, rb4[3].y); v1.w = f2bf_pair(rb4[3].z, rb4[3].w);
      uint4* pb = (uint4*)&ldb[arow*40 + kb];
      pb[0] = v0; pb[1] = v1;
    }
    if (ks < 15){
      const int k0 = (ks+1)*32;
      const uint4* p0 = (const uint4*)(ctx0 + rgs*512 + k0 + kb);
      ra0[0]=p0[0]; ra0[1]=p0[1];
      const uint4* p1 = (const uint4*)(ctx1 + rgs*512 + k0 + kb);
      ra1[0]=p1[0]; ra1[1]=p1[1];
      const int h = (k0+kb)>>6;
      l0 = lb0[h*1024]; l1 = lb1[h*1024];
      const float4* pq = (const float4*)(Wo + (c0+arow)*512 + k0 + kb);
      rb4[0]=pq[0]; rb4[1]=pq[1]; rb4[2]=pq[2]; rb4[3]=pq[3];
    }
    bar_lgkm();
    #pragma unroll
    for (int kf=0; kf<2; ++kf){
      bf16x8 af0 = *(const bf16x8*)&lda[(wr+lo)*40    + kf*16 + hi*8];
      bf16x8 af1 = *(const bf16x8*)&lda[(wr+32+lo)*40 + kf*16 + hi*8];
      bf16x8 bg0 = *(const bf16x8*)&ldb[(wc+lo)*40    + kf*16 + hi*8];
      bf16x8 bg1 = *(const bf16x8*)&ldb[(wc+32+lo)*40 + kf*16 + hi*8];
      acc[0][0] = __builtin_amdgcn_mfma_f32_32x32x16_bf16(af0, bg0, acc[0][0], 0,0,0);
      acc[0][1] = __builtin_amdgcn_mfma_f32_32x32x16_bf16(af0, bg1, acc[0][1], 0,0,0);
      acc[1][0] = __builtin_amdgcn_mfma_f32_32x32x16_bf16(af1, bg0, acc[1][0], 0,0,0);
      acc[1][1] = __builtin_amdgcn_mfma_f32_32x32x16_bf16(af1, bg1, acc[1][1], 0,0,0);
    }
  }

  #pragma unroll
  for (int mi=0;mi<2;mi++){
    #pragma unroll
    for (int ni=0;ni<2;ni++){
      #pragma unroll
      for (int r=0;r<16;r++){
        const int rl = wr + mi*32 + (r&3) + 8*(r>>2) + 4*hi;
        const int cl = wc + ni*32 + lo;
        const int rg = r0 + rl, cg = c0 + cl;
        OUT[rg*512 + cg] = acc[mi][ni][r] + bo[cg];
      }
    }
  }
}

// ---------------------------------------------------------------------------
// Fused attention, t-split across blocks. Grid (32 q-tiles, B*2), 512 thr =
// 8 waves = 8 heads; block handles t in [ts*512, ts*512+512). R1 structure:
// abt LDS double-buffer (1 raw barrier/iter), K/V register prefetch.
// Outputs UNNORMALIZED partial ctx (bf16) + partial row-sums (f32).
// NOTE: no min-waves launch_bounds hint — it forces VGPR=64 and spills (R5/R7).
// ---------------------------------------------------------------------------
__global__ __launch_bounds__(512)
void attn_fused(const unsigned short* qh, const unsigned short* kh,
                const unsigned short* vhT, const int* ab,
                const float* bias_table, const float* vbias,
                unsigned short* ctxp, float* lsump)
{
  __shared__ float tbl[8*260];        // per-head: [0..254]=table*log2e, 255=-inf, 256=vbias*log2e
  __shared__ int   abt[2][32*33];     // bias-index tile, double-buffered, TRANSPOSED [t][q], padded
  __shared__ float pbuf[8][32*33];    // per-wave P bounce, [q][t] f32, padded

  const int tid = threadIdx.x;
  const int b   = blockIdx.y >> 1;
  const int ts  = blockIdx.y & 1;     // t-split half
  const int s0  = blockIdx.x*32;
  const int tb  = ts*512;

  for (int i = tid; i < 8*257; i += 512){
    const int h = i/257, idx = i - h*257;
    float v;
    if (idx < 255)       v = bias_table[idx*8 + h];
    else if (idx == 255) v = -1.0e30f;      // ab==255 -> -inf mask
    else                 v = vbias[h];      // global row/col
    tbl[h*260 + idx] = v * 1.4426950408889634f;
  }

  const int w = tid>>6, lane = tid&63, lo = lane&31, hi = lane>>5;
  const unsigned short* qbase = qh  + (size_t)(b*8+w)*1024*64;
  const unsigned short* kbase = kh  + (size_t)(b*8+w)*1024*64;
  const unsigned short* vbase = vhT + (size_t)(b*8+w)*64*1024;

  // Q fragments (A operand, rows = s0+lo, k=d), held across the whole t loop
  bf16x8 qf[4];
  #pragma unroll
  for (int kf=0; kf<4; ++kf)
    qf[kf] = *(const bf16x8*)&qbase[(s0+lo)*64 + kf*16 + hi*8];

  f32x16 accv[2]; accv[0] = zero16(); accv[1] = zero16();
  float lsum[16];
  #pragma unroll
  for (int r=0;r<16;r++) lsum[r] = 0.0f;

  const int e0   = tid*2;
  const int str  = e0>>5;      // staging q-row
  const int stc  = e0&31;      // staging t-col (even)
  const int srow = s0 + str;
  const size_t abrow = (size_t)(b*1023 + srow)*1023;

  // ---- prefetch tile 0 ----
  int av0 = 256, av1 = 256;
  if (srow < 1023){
    if (tb + stc     < 1023) av0 = ab[abrow + tb + stc];
    if (tb + stc + 1 < 1023) av1 = ab[abrow + tb + stc + 1];
  }
  bf16x8 kc[4], kn[4], vc[4], vn[4];
  #pragma unroll
  for (int i=0;i<4;i++) kc[i] = *(const bf16x8*)&kbase[(tb+lo)*64 + i*16 + hi*8];
  #pragma unroll
  for (int dc=0;dc<2;dc++)
    #pragma unroll
    for (int j=0;j<2;j++)
      vc[dc*2+j] = *(const bf16x8*)&vbase[(dc*32+lo)*1024 + tb + j*16 + hi*8];

  for (int tt=0; tt<512; tt+=32){
    const int cur = (tt>>5)&1;
    const int tn  = tb + ((tt+32)&511);        // wrapped prefetch target (last iter unused)
    // stage abt[cur] from prefetched regs (vmcnt wait happens here, 1 iter of slack)
    abt[cur][(stc  )*33 + str] = av0;
    abt[cur][(stc+1)*33 + str] = av1;
    // issue next ab loads
    int na0 = 256, na1 = 256;
    if (tt < 480 && srow < 1023){
      const int tc = tb + tt + 32 + stc;
      if (tc     < 1023) na0 = ab[abrow + tc];
      if (tc + 1 < 1023) na1 = ab[abrow + tc + 1];
    }

    // scores tile [32q x 32t] = Q * K^T (K prefetched last iter)
    f32x16 sc = zero16();
    sc = __builtin_amdgcn_mfma_f32_32x32x16_bf16(qf[0], kc[0], sc, 0,0,0);
    sc = __builtin_amdgcn_mfma_f32_32x32x16_bf16(qf[1], kc[1], sc, 0,0,0);
    sc = __builtin_amdgcn_mfma_f32_32x32x16_bf16(qf[2], kc[2], sc, 0,0,0);
    sc = __builtin_amdgcn_mfma_f32_32x32x16_bf16(qf[3], kc[3], sc, 0,0,0);
    // issue next K loads (in flight across the barrier)
    #pragma unroll
    for (int i=0;i<4;i++) kn[i] = *(const bf16x8*)&kbase[(tn+lo)*64 + i*16 + hi*8];

    // abt[cur] visible to all waves; vmcnt NOT drained (raw barrier)
    bar_lgkm();

    // bias lookup + exp2; truncate p to bf16 (consistently for lsum and P)
    #pragma unroll
    for (int r=0;r<16;r++){
      const int rq  = (r&3) + 8*(r>>2) + 4*hi;   // q row of this acc reg
      const int idx = abt[cur][lo*33 + rq];      // read transposed: row=t(lo), col=q
      const float bv = tbl[w*260 + idx];
      float p = __builtin_amdgcn_exp2f(sc[r] + bv);
      p = __uint_as_float(__float_as_uint(p) & 0xffff0000u);
      lsum[r] += p;
      pbuf[w][rq*33 + lo] = p;                   // [q][t], conflict-free (33 pad)
    }
    asm volatile("s_waitcnt lgkmcnt(0)" ::: "memory");  // P bounce RAW within wave

    // read P as A fragments (row=lo, k=t consecutive), pack truncated bf16 pairs
    unsigned pf[2][4];
    #pragma unroll
    for (int kf=0; kf<2; ++kf){
      #pragma unroll
      for (int pr=0; pr<4; ++pr){
        const float a = pbuf[w][lo*33 + kf*16 + hi*8 + 2*pr];
        const float c = pbuf[w][lo*33 + kf*16 + hi*8 + 2*pr + 1];
        pf[kf][pr] = (__float_as_uint(a)>>16) | (__float_as_uint(c) & 0xffff0000u);
      }
    }
    // issue next V loads
    #pragma unroll
    for (int dc=0;dc<2;dc++)
      #pragma unroll
      for (int j=0;j<2;j++)
        vn[dc*2+j] = *(const bf16x8*)&vbase[(dc*32+lo)*1024 + tn + j*16 + hi*8];

    // PV: ctx[32q x 64d] += P * V
    #pragma unroll
    for (int dc=0; dc<2; ++dc){
      #pragma unroll
      for (int kf=0; kf<2; ++kf){
        union { unsigned u[4]; bf16x8 v; } pc;
        pc.u[0]=pf[kf][0]; pc.u[1]=pf[kf][1]; pc.u[2]=pf[kf][2]; pc.u[3]=pf[kf][3];
        accv[dc] = __builtin_amdgcn_mfma_f32_32x32x16_bf16(pc.v, vc[dc*2+kf], accv[dc], 0,0,0);
      }
    }
    // rotate prefetch buffers
    av0 = na0; av1 = na1;
    #pragma unroll
    for (int i=0;i<4;i++){ kc[i] = kn[i]; vc[i] = vn[i]; }
  }

  // partial row sums: reduce over the 32 lanes (t-cols) sharing each row
  #pragma unroll
  for (int r=0;r<16;r++){
    #pragma unroll
    for (int m=1;m<32;m<<=1) lsum[r] += __shfl_xor(lsum[r], m, 64);
  }
  // store UNNORMALIZED partial ctx bf16 (this half's slice) + partial lsum
  unsigned short* cbase = ctxp + (size_t)ts*4194304;   // 8*1024*512 elements per half
  #pragma unroll
  for (int dc=0; dc<2; ++dc){
    #pragma unroll
    for (int r=0;r<16;r++){
      const int rq = (r&3) + 8*(r>>2) + 4*hi;
      cbase[((size_t)b*1024 + s0 + rq)*512 + w*64 + dc*32 + lo] = f2bf(accv[dc][r]);
    }
  }
  if (lo == 0){
    #pragma unroll
    for (int r=0;r<16;r++){
      const int rq = (r&3) + 8*(r>>2) + 4*hi;
      lsump[((size_t)(ts*8 + b)*8 + w)*1024 + s0 + rq] = lsum[r];
    }
  }
}

extern "C" void kernel_launch(void* const* d_in, const int* in_sizes, int n_in,
                              void* d_out, int out_size, void* d_ws, size_t ws_size,
                              hipStream_t stream)
{
  const float* q    = (const float*)d_in[0];
  const float* k    = (const float*)d_in[1];
  const float* v    = (const float*)d_in[2];
  const int*   ab   = (const int*)  d_in[3];
  const float* Wq   = (const float*)d_in[4];
  const float* bq   = (const float*)d_in[5];
  const float* Wk   = (const float*)d_in[6];
  const float* bk   = (const float*)d_in[7];
  const float* Wv   = (const float*)d_in[8];
  const float* bv   = (const float*)d_in[9];
  const float* Wo   = (const float*)d_in[10];
  const float* bo   = (const float*)d_in[11];
  const float* btab = (const float*)d_in[12];
  const float* vbia = (const float*)d_in[13];

  char* ws = (char*)d_ws;
  unsigned short* qh   = (unsigned short*)(ws);                    //  8 MB
  unsigned short* kh   = (unsigned short*)(ws + ((size_t) 8<<20)); //  8 MB
  unsigned short* vhT  = (unsigned short*)(ws + ((size_t)16<<20)); //  8 MB
  unsigned short* ctxp = (unsigned short*)(ws + ((size_t)24<<20)); // 16 MB (2 halves)
  float*          lsmp = (float*)         (ws + ((size_t)40<<20)); // 512 KB

  const float SCALE_Q = 0.125f * 1.4426950408889634f;  // D^-0.5 * log2(e)

  qkv_proj<<<768, 256, 0, stream>>>(q, k, v, Wq, Wk, Wv, bq, bk, bv,
                                    qh, kh, vhT, SCALE_Q);
  attn_fused<<<dim3(32,16), 512, 0, stream>>>(qh, kh, vhT, ab, btab, vbia,
                                              ctxp, lsmp);
  out_proj<<<dim3(64,4), 256, 0, stream>>>(ctxp, ctxp + (size_t)4194304,
                                           lsmp, Wo, bo, (float*)d_out);
}